// Round 1
// baseline (857.074 us; speedup 1.0000x reference)
//
#include <hip/hip_runtime.h>
#include <hip/hip_bf16.h>

#define N_NODES 100000
#define N_EDGES 1600000
#define IN_DIM 128
#define HID 128
#define NC 40

// ---------------- degree / normalization ----------------

__global__ void count_deg_kernel(const int* __restrict__ ei, int* __restrict__ deg) {
    int e = blockIdx.x * 256 + threadIdx.x;   // grid sized exactly E/256
    int c = ei[N_EDGES + e];                  // col = ei[1][e]
    atomicAdd(&deg[c], 1);
}

__global__ void dis_kernel(const int* __restrict__ deg, float* __restrict__ dis) {
    int i = blockIdx.x * 256 + threadIdx.x;
    if (i < N_NODES) dis[i] = rsqrtf((float)deg[i] + 1.0f);
}

// ---------------- CSR build: 3-step scan + fill ----------------

__global__ void scan_partial_kernel(const int* __restrict__ deg, int* __restrict__ bsums) {
    __shared__ int s[256];
    int i = blockIdx.x * 256 + threadIdx.x;
    int v = (i < N_NODES) ? deg[i] : 0;
    s[threadIdx.x] = v;
    __syncthreads();
    for (int off = 128; off > 0; off >>= 1) {
        if (threadIdx.x < off) s[threadIdx.x] += s[threadIdx.x + off];
        __syncthreads();
    }
    if (threadIdx.x == 0) bsums[blockIdx.x] = s[0];
}

__global__ void scan_bsums_kernel(int* __restrict__ bsums, int nb) {
    __shared__ int s[512];
    int v = (threadIdx.x < nb) ? bsums[threadIdx.x] : 0;
    s[threadIdx.x] = v;
    __syncthreads();
    for (int off = 1; off < 512; off <<= 1) {
        int t = (threadIdx.x >= off) ? s[threadIdx.x - off] : 0;
        __syncthreads();
        s[threadIdx.x] += t;
        __syncthreads();
    }
    if (threadIdx.x < nb) bsums[threadIdx.x] = s[threadIdx.x] - v;  // exclusive
}

__global__ void scan_final_kernel(const int* __restrict__ deg, const int* __restrict__ bsums,
                                  int* __restrict__ row_ptr) {
    __shared__ int s[256];
    int i = blockIdx.x * 256 + threadIdx.x;
    int v = (i < N_NODES) ? deg[i] : 0;
    s[threadIdx.x] = v;
    __syncthreads();
    for (int off = 1; off < 256; off <<= 1) {
        int t = (threadIdx.x >= off) ? s[threadIdx.x - off] : 0;
        __syncthreads();
        s[threadIdx.x] += t;
        __syncthreads();
    }
    if (i < N_NODES) row_ptr[i] = s[threadIdx.x] - v + bsums[blockIdx.x];
    if (i == 0) row_ptr[N_NODES] = N_EDGES;
}

__global__ void fill_adj_kernel(const int* __restrict__ ei, int* __restrict__ fill,
                                const int* __restrict__ row_ptr, int* __restrict__ adj) {
    int e = blockIdx.x * 256 + threadIdx.x;
    int r = ei[e];
    int c = ei[N_EDGES + e];
    int pos = row_ptr[c] + atomicAdd(&fill[c], 1);
    adj[pos] = r;
}

// ---------------- fp32 GEMM: C[N,128] = A[N,128(lda)] * W[128,128] ----------------
// block 256 threads, tile 32 rows x 128 cols, 4x4 register blocking.

__global__ __launch_bounds__(256) void gemm128_kernel(const float* __restrict__ A, int lda,
                                                      const float* __restrict__ W,
                                                      float* __restrict__ C) {
    __shared__ float As[32][128];
    int tx = threadIdx.x;
    int rb = blockIdx.x * 32;   // N divisible by 32

#pragma unroll
    for (int i = 0; i < 4; i++) {
        int idx = tx + 256 * i;
        int r = idx >> 5;
        int c4 = (idx & 31) << 2;
        *(float4*)&As[r][c4] = *(const float4*)&A[(size_t)(rb + r) * lda + c4];
    }
    __syncthreads();

    int col = (tx & 31) << 2;
    int rq = tx >> 5;   // 0..7
    float acc[4][4];
#pragma unroll
    for (int j = 0; j < 4; j++)
#pragma unroll
        for (int jj = 0; jj < 4; jj++) acc[j][jj] = 0.f;

    for (int k = 0; k < 128; k += 4) {
        float4 a[4];
#pragma unroll
        for (int j = 0; j < 4; j++) a[j] = *(const float4*)&As[rq + 8 * j][k];
#pragma unroll
        for (int kk = 0; kk < 4; kk++) {
            float4 w = *(const float4*)&W[(size_t)(k + kk) * 128 + col];
#pragma unroll
            for (int j = 0; j < 4; j++) {
                float av = ((const float*)&a[j])[kk];
                acc[j][0] = fmaf(av, w.x, acc[j][0]);
                acc[j][1] = fmaf(av, w.y, acc[j][1]);
                acc[j][2] = fmaf(av, w.z, acc[j][2]);
                acc[j][3] = fmaf(av, w.w, acc[j][3]);
            }
        }
    }

#pragma unroll
    for (int j = 0; j < 4; j++) {
        *(float4*)&C[(size_t)(rb + rq + 8 * j) * 128 + col] =
            make_float4(acc[j][0], acc[j][1], acc[j][2], acc[j][3]);
    }
}

// ---------------- aggregation: out = relu(D^-1/2 (A+I) D^-1/2 h + b) ----------------
// one block (128 threads) per node; gather-based, no atomics.

__global__ __launch_bounds__(128) void agg_kernel(const float* __restrict__ h,
                                                  const float* __restrict__ dis,
                                                  const int* __restrict__ row_ptr,
                                                  const int* __restrict__ adj,
                                                  const float* __restrict__ bias,
                                                  float* __restrict__ out, int ldo) {
    int c = blockIdx.x;
    int f = threadIdx.x;
    float dc = dis[c];
    float acc = h[(size_t)c * 128 + f] * dc * dc;   // self loop
    int p0 = row_ptr[c], p1 = row_ptr[c + 1];
    for (int p = p0; p < p1; p++) {
        int s = adj[p];
        acc = fmaf(h[(size_t)s * 128 + f] * dis[s], dc, acc);
    }
    float v = fmaxf(acc + bias[f], 0.f);
    out[(size_t)c * ldo + f] = v;
}

// ---------------- classifier: logits = h2 @ cls_w + cls_b, dual write ----------------

__global__ __launch_bounds__(256) void classifier_kernel(const float* __restrict__ A, int lda,
                                                         const float* __restrict__ Wc,
                                                         const float* __restrict__ bc,
                                                         float* __restrict__ out1,
                                                         float* __restrict__ out2) {
    __shared__ float Hs[32][128];
    int tx = threadIdx.x;
    int rb = blockIdx.x * 32;
#pragma unroll
    for (int i = 0; i < 4; i++) {
        int idx = tx + 256 * i;
        int r = idx >> 5;
        int c4 = (idx & 31) << 2;
        *(float4*)&Hs[r][c4] = *(const float4*)&A[(size_t)(rb + r) * lda + c4];
    }
    __syncthreads();

    int j = tx & 63;
    int ry = tx >> 6;   // 0..3
    if (j < NC) {
        float acc[8];
#pragma unroll
        for (int i = 0; i < 8; i++) acc[i] = bc[j];
        for (int k = 0; k < 128; k++) {
            float w = Wc[(size_t)k * NC + j];
#pragma unroll
            for (int i = 0; i < 8; i++) acc[i] = fmaf(Hs[ry + 4 * i][k], w, acc[i]);
        }
#pragma unroll
        for (int i = 0; i < 8; i++) {
            int r = rb + ry + 4 * i;
            out1[(size_t)r * NC + j] = acc[i];
            out2[(size_t)r * 296 + j] = acc[i];
        }
    }
}

// ---------------- launch ----------------

extern "C" void kernel_launch(void* const* d_in, const int* in_sizes, int n_in,
                              void* d_out, int out_size, void* d_ws, size_t ws_size,
                              hipStream_t stream) {
    (void)in_sizes; (void)n_in; (void)out_size; (void)ws_size;

    const float* x     = (const float*)d_in[0];
    const int*   ei    = (const int*)d_in[1];
    const float* w0    = (const float*)d_in[2];
    const float* b0    = (const float*)d_in[3];
    const float* w1    = (const float*)d_in[4];
    const float* b1    = (const float*)d_in[5];
    const float* cls_w = (const float*)d_in[6];
    const float* cls_b = (const float*)d_in[7];

    float* logits = (float*)d_out;
    float* feat   = logits + (size_t)N_NODES * NC;   // [N,296]: h1 | h2 | logits

    char* ws = (char*)d_ws;
    int*   deg     = (int*)(ws + 0);          // N ints
    float* dis     = (float*)(ws + 400000);   // N floats
    int*   row_ptr = (int*)(ws + 800000);     // N+1 ints (padded)
    int*   fill    = (int*)(ws + 1200016);    // N ints
    int*   adj     = (int*)(ws + 1600016);    // E ints
    float* h       = (float*)(ws + 8000016);  // N*128 floats
    int*   bsums   = (int*)(ws + 59200016);   // 391 ints

    const int NB = (N_NODES + 255) / 256;     // 391

    hipMemsetAsync(deg, 0, (size_t)N_NODES * 4, stream);
    hipMemsetAsync(fill, 0, (size_t)N_NODES * 4, stream);

    count_deg_kernel<<<N_EDGES / 256, 256, 0, stream>>>(ei, deg);
    dis_kernel<<<NB, 256, 0, stream>>>(deg, dis);
    scan_partial_kernel<<<NB, 256, 0, stream>>>(deg, bsums);
    scan_bsums_kernel<<<1, 512, 0, stream>>>(bsums, NB);
    scan_final_kernel<<<NB, 256, 0, stream>>>(deg, bsums, row_ptr);
    fill_adj_kernel<<<N_EDGES / 256, 256, 0, stream>>>(ei, fill, row_ptr, adj);

    // layer 1
    gemm128_kernel<<<N_NODES / 32, 256, 0, stream>>>(x, 128, w0, h);
    agg_kernel<<<N_NODES, 128, 0, stream>>>(h, dis, row_ptr, adj, b0, feat + 0, 296);
    // layer 2
    gemm128_kernel<<<N_NODES / 32, 256, 0, stream>>>(feat, 296, w1, h);
    agg_kernel<<<N_NODES, 128, 0, stream>>>(h, dis, row_ptr, adj, b1, feat + 128, 296);
    // classifier (writes logits region + feat[:,256:296])
    classifier_kernel<<<N_NODES / 32, 256, 0, stream>>>(feat + 128, 296, cls_w, cls_b,
                                                        logits, feat + 256);
}

// Round 2
// 635.536 us; speedup vs baseline: 1.3486x; 1.3486x over previous
//
#include <hip/hip_runtime.h>
#include <hip/hip_bf16.h>

#define N_NODES 100000
#define N_EDGES 1600000
#define IN_DIM 128
#define HID 128
#define NC 40

// ---- bf16 helpers (packed 2x16 in a uint) ----
__device__ __forceinline__ float bflo(unsigned u) { return __uint_as_float(u << 16); }
__device__ __forceinline__ float bfhi(unsigned u) { return __uint_as_float(u & 0xffff0000u); }
__device__ __forceinline__ unsigned f2bf(float f) {            // RNE, returns 16-bit pattern
    unsigned u = __float_as_uint(f);
    return (u + 0x7fffu + ((u >> 16) & 1u)) >> 16;
}

// ---------------- degree / normalization ----------------

__global__ void count_deg_kernel(const int* __restrict__ ei, int* __restrict__ deg) {
    int e = blockIdx.x * 256 + threadIdx.x;
    int c = ei[N_EDGES + e];
    atomicAdd(&deg[c], 1);
}

__global__ void dis_kernel(const int* __restrict__ deg, float* __restrict__ dis) {
    int i = blockIdx.x * 256 + threadIdx.x;
    if (i < N_NODES) dis[i] = rsqrtf((float)deg[i] + 1.0f);
}

// ---------------- CSR build: 3-step scan + fill ----------------

__global__ void scan_partial_kernel(const int* __restrict__ deg, int* __restrict__ bsums) {
    __shared__ int s[256];
    int i = blockIdx.x * 256 + threadIdx.x;
    int v = (i < N_NODES) ? deg[i] : 0;
    s[threadIdx.x] = v;
    __syncthreads();
    for (int off = 128; off > 0; off >>= 1) {
        if (threadIdx.x < off) s[threadIdx.x] += s[threadIdx.x + off];
        __syncthreads();
    }
    if (threadIdx.x == 0) bsums[blockIdx.x] = s[0];
}

__global__ void scan_bsums_kernel(int* __restrict__ bsums, int nb) {
    __shared__ int s[512];
    int v = (threadIdx.x < nb) ? bsums[threadIdx.x] : 0;
    s[threadIdx.x] = v;
    __syncthreads();
    for (int off = 1; off < 512; off <<= 1) {
        int t = (threadIdx.x >= off) ? s[threadIdx.x - off] : 0;
        __syncthreads();
        s[threadIdx.x] += t;
        __syncthreads();
    }
    if (threadIdx.x < nb) bsums[threadIdx.x] = s[threadIdx.x] - v;  // exclusive
}

__global__ void scan_final_kernel(const int* __restrict__ deg, const int* __restrict__ bsums,
                                  int* __restrict__ row_ptr) {
    __shared__ int s[256];
    int i = blockIdx.x * 256 + threadIdx.x;
    int v = (i < N_NODES) ? deg[i] : 0;
    s[threadIdx.x] = v;
    __syncthreads();
    for (int off = 1; off < 256; off <<= 1) {
        int t = (threadIdx.x >= off) ? s[threadIdx.x - off] : 0;
        __syncthreads();
        s[threadIdx.x] += t;
        __syncthreads();
    }
    if (i < N_NODES) row_ptr[i] = s[threadIdx.x] - v + bsums[blockIdx.x];
    if (i == 0) row_ptr[N_NODES] = N_EDGES;
}

__global__ void fill_adj_kernel(const int* __restrict__ ei, int* __restrict__ fill,
                                const int* __restrict__ row_ptr, int* __restrict__ adj) {
    int e = blockIdx.x * 256 + threadIdx.x;
    int r = ei[e];
    int c = ei[N_EDGES + e];
    int pos = row_ptr[c] + atomicAdd(&fill[c], 1);
    adj[pos] = r;
}

// ---------------- fp32 GEMM: Cb[N,128](bf16) = A[N,128(lda)] * W[128,128] ----------------
// W staged in LDS (64 KB); tile 32 rows x 128 cols; 4x4 register blocking.

__global__ __launch_bounds__(256) void gemm128_kernel(const float* __restrict__ A, int lda,
                                                      const float* __restrict__ W,
                                                      unsigned short* __restrict__ Cb) {
    __shared__ float As[32][128];
    __shared__ float Ws[128][128];
    int tx = threadIdx.x;
    int rb = blockIdx.x * 32;

#pragma unroll
    for (int i = 0; i < 16; i++) {          // 16384 floats = 4096 float4 / 256 threads
        int f = tx + 256 * i;
        ((float4*)Ws)[f] = ((const float4*)W)[f];
    }
#pragma unroll
    for (int i = 0; i < 4; i++) {
        int idx = tx + 256 * i;
        int r = idx >> 5;
        int c4 = (idx & 31) << 2;
        *(float4*)&As[r][c4] = *(const float4*)&A[(size_t)(rb + r) * lda + c4];
    }
    __syncthreads();

    int col = (tx & 31) << 2;
    int rq = tx >> 5;   // 0..7
    float acc[4][4];
#pragma unroll
    for (int j = 0; j < 4; j++)
#pragma unroll
        for (int jj = 0; jj < 4; jj++) acc[j][jj] = 0.f;

    for (int k = 0; k < 128; k += 4) {
        float4 a[4];
#pragma unroll
        for (int j = 0; j < 4; j++) a[j] = *(const float4*)&As[rq + 8 * j][k];
#pragma unroll
        for (int kk = 0; kk < 4; kk++) {
            float4 w = *(const float4*)&Ws[k + kk][col];
#pragma unroll
            for (int j = 0; j < 4; j++) {
                float av = ((const float*)&a[j])[kk];
                acc[j][0] = fmaf(av, w.x, acc[j][0]);
                acc[j][1] = fmaf(av, w.y, acc[j][1]);
                acc[j][2] = fmaf(av, w.z, acc[j][2]);
                acc[j][3] = fmaf(av, w.w, acc[j][3]);
            }
        }
    }

#pragma unroll
    for (int j = 0; j < 4; j++) {
        unsigned lo = f2bf(acc[j][0]) | (f2bf(acc[j][1]) << 16);
        unsigned hi = f2bf(acc[j][2]) | (f2bf(acc[j][3]) << 16);
        *(uint2*)&Cb[(size_t)(rb + rq + 8 * j) * 128 + col] = make_uint2(lo, hi);
    }
}

// ---------------- aggregation: out = relu(D^-1/2 (A+I) D^-1/2 h + b) ----------------
// one wave (64 lanes) per node, bf16x2 per lane; unroll-4 neighbor ILP; no atomics.

__global__ __launch_bounds__(256) void agg_kernel(const unsigned* __restrict__ hb,
                                                  const float* __restrict__ dis,
                                                  const int* __restrict__ row_ptr,
                                                  const int* __restrict__ adj,
                                                  const float* __restrict__ bias,
                                                  float* __restrict__ out, int ldo) {
    int node = __builtin_amdgcn_readfirstlane(blockIdx.x * 4 + (threadIdx.x >> 6));
    int lane = threadIdx.x & 63;
    float dc = dis[node];
    int p0 = row_ptr[node], p1 = row_ptr[node + 1];

    unsigned sv = hb[(size_t)node * 64 + lane];
    float a0 = bflo(sv) * dc * dc, a1 = bfhi(sv) * dc * dc;   // self loop
    float b0 = 0.f, b1 = 0.f, c0 = 0.f, c1 = 0.f, d0 = 0.f, d1 = 0.f;

    int p = p0;
    for (; p + 4 <= p1; p += 4) {
        int s0 = adj[p + 0], s1 = adj[p + 1], s2 = adj[p + 2], s3 = adj[p + 3];
        unsigned v0 = hb[(size_t)s0 * 64 + lane];
        unsigned v1 = hb[(size_t)s1 * 64 + lane];
        unsigned v2 = hb[(size_t)s2 * 64 + lane];
        unsigned v3 = hb[(size_t)s3 * 64 + lane];
        float w0 = dis[s0] * dc, w1 = dis[s1] * dc;
        float w2 = dis[s2] * dc, w3 = dis[s3] * dc;
        a0 = fmaf(bflo(v0), w0, a0); a1 = fmaf(bfhi(v0), w0, a1);
        b0 = fmaf(bflo(v1), w1, b0); b1 = fmaf(bfhi(v1), w1, b1);
        c0 = fmaf(bflo(v2), w2, c0); c1 = fmaf(bfhi(v2), w2, c1);
        d0 = fmaf(bflo(v3), w3, d0); d1 = fmaf(bfhi(v3), w3, d1);
    }
    for (; p < p1; p++) {
        int s = adj[p];
        unsigned v = hb[(size_t)s * 64 + lane];
        float w = dis[s] * dc;
        a0 = fmaf(bflo(v), w, a0); a1 = fmaf(bfhi(v), w, a1);
    }

    float2 bi = *(const float2*)&bias[lane * 2];
    float r0 = fmaxf((a0 + b0) + (c0 + d0) + bi.x, 0.f);
    float r1 = fmaxf((a1 + b1) + (c1 + d1) + bi.y, 0.f);
    *(float2*)&out[(size_t)node * ldo + lane * 2] = make_float2(r0, r1);
}

// ---------------- classifier: logits = h2 @ cls_w + cls_b, dual write ----------------

__global__ __launch_bounds__(256) void classifier_kernel(const float* __restrict__ A, int lda,
                                                         const float* __restrict__ Wc,
                                                         const float* __restrict__ bc,
                                                         float* __restrict__ out1,
                                                         float* __restrict__ out2) {
    __shared__ float Hs[32][128];
    int tx = threadIdx.x;
    int rb = blockIdx.x * 32;
#pragma unroll
    for (int i = 0; i < 4; i++) {
        int idx = tx + 256 * i;
        int r = idx >> 5;
        int c4 = (idx & 31) << 2;
        *(float4*)&Hs[r][c4] = *(const float4*)&A[(size_t)(rb + r) * lda + c4];
    }
    __syncthreads();

    int j = tx & 63;
    int ry = tx >> 6;   // 0..3
    if (j < NC) {
        float acc[8];
#pragma unroll
        for (int i = 0; i < 8; i++) acc[i] = bc[j];
        for (int k = 0; k < 128; k++) {
            float w = Wc[(size_t)k * NC + j];
#pragma unroll
            for (int i = 0; i < 8; i++) acc[i] = fmaf(Hs[ry + 4 * i][k], w, acc[i]);
        }
#pragma unroll
        for (int i = 0; i < 8; i++) {
            int r = rb + ry + 4 * i;
            out1[(size_t)r * NC + j] = acc[i];
            out2[(size_t)r * 296 + j] = acc[i];
        }
    }
}

// ---------------- launch ----------------

extern "C" void kernel_launch(void* const* d_in, const int* in_sizes, int n_in,
                              void* d_out, int out_size, void* d_ws, size_t ws_size,
                              hipStream_t stream) {
    (void)in_sizes; (void)n_in; (void)out_size; (void)ws_size;

    const float* x     = (const float*)d_in[0];
    const int*   ei    = (const int*)d_in[1];
    const float* w0    = (const float*)d_in[2];
    const float* b0    = (const float*)d_in[3];
    const float* w1    = (const float*)d_in[4];
    const float* b1    = (const float*)d_in[5];
    const float* cls_w = (const float*)d_in[6];
    const float* cls_b = (const float*)d_in[7];

    float* logits = (float*)d_out;
    float* feat   = logits + (size_t)N_NODES * NC;   // [N,296]: h1 | h2 | logits

    char* ws = (char*)d_ws;
    int*            deg     = (int*)(ws + 0);          // N ints
    float*          dis     = (float*)(ws + 400000);   // N floats
    int*            row_ptr = (int*)(ws + 800000);     // N+1 ints (padded)
    int*            fill    = (int*)(ws + 1200016);    // N ints
    int*            adj     = (int*)(ws + 1600016);    // E ints
    unsigned short* hb      = (unsigned short*)(ws + 8000016);  // N*128 bf16
    int*            bsums   = (int*)(ws + 59200016);   // 391 ints

    const int NB = (N_NODES + 255) / 256;   // 391

    hipMemsetAsync(deg, 0, (size_t)N_NODES * 4, stream);
    hipMemsetAsync(fill, 0, (size_t)N_NODES * 4, stream);

    count_deg_kernel<<<N_EDGES / 256, 256, 0, stream>>>(ei, deg);
    dis_kernel<<<NB, 256, 0, stream>>>(deg, dis);
    scan_partial_kernel<<<NB, 256, 0, stream>>>(deg, bsums);
    scan_bsums_kernel<<<1, 512, 0, stream>>>(bsums, NB);
    scan_final_kernel<<<NB, 256, 0, stream>>>(deg, bsums, row_ptr);
    fill_adj_kernel<<<N_EDGES / 256, 256, 0, stream>>>(ei, fill, row_ptr, adj);

    // layer 1
    gemm128_kernel<<<N_NODES / 32, 256, 0, stream>>>(x, 128, w0, hb);
    agg_kernel<<<N_NODES / 4, 256, 0, stream>>>((const unsigned*)hb, dis, row_ptr, adj, b0,
                                                feat + 0, 296);
    // layer 2
    gemm128_kernel<<<N_NODES / 32, 256, 0, stream>>>(feat, 296, w1, hb);
    agg_kernel<<<N_NODES / 4, 256, 0, stream>>>((const unsigned*)hb, dis, row_ptr, adj, b1,
                                                feat + 128, 296);
    // classifier (writes logits region + feat[:,256:296])
    classifier_kernel<<<N_NODES / 32, 256, 0, stream>>>(feat + 128, 296, cls_w, cls_b,
                                                        logits, feat + 256);
}

// Round 3
// 620.775 us; speedup vs baseline: 1.3807x; 1.0238x over previous
//
#include <hip/hip_runtime.h>
#include <hip/hip_bf16.h>

#define N_NODES 100000
#define N_EDGES 1600000
#define NC 40

#define GEMM_BLOCKS 3125      // N_NODES/32
#define FILL_PASSES 8
#define FILL_RANGE  12500     // N_NODES/FILL_PASSES
#define FILL_CHUNK  2048      // edges per block (256 thr x 8)
#define FILL_CHUNKS 782       // ceil(N_EDGES/FILL_CHUNK)
#define FILL_BLOCKS (FILL_PASSES * FILL_CHUNKS)

// ---- bf16 helpers (packed 2x16 in a uint) ----
__device__ __forceinline__ float bflo(unsigned u) { return __uint_as_float(u << 16); }
__device__ __forceinline__ float bfhi(unsigned u) { return __uint_as_float(u & 0xffff0000u); }
__device__ __forceinline__ unsigned f2bf(float f) {
    unsigned u = __float_as_uint(f);
    return (u + 0x7fffu + ((u >> 16) & 1u)) >> 16;
}

// ---------------- degree ----------------
// fire-and-forget atomics (no return value -> no wait), 8 edges/thread
__global__ __launch_bounds__(256) void count_deg_kernel(const int* __restrict__ ei,
                                                        int* __restrict__ deg) {
    int base = blockIdx.x * FILL_CHUNK + threadIdx.x;
#pragma unroll
    for (int j = 0; j < 8; j++) {
        int e = base + 256 * j;
        if (e < N_EDGES) atomicAdd(&deg[ei[N_EDGES + e]], 1);
    }
}

// ---------------- CSR scan (3 kernels) ----------------

__global__ void scan_partial_kernel(const int* __restrict__ deg, int* __restrict__ bsums,
                                    float* __restrict__ dis) {
    __shared__ int s[256];
    int i = blockIdx.x * 256 + threadIdx.x;
    int v = (i < N_NODES) ? deg[i] : 0;
    if (i < N_NODES) dis[i] = rsqrtf((float)v + 1.0f);
    s[threadIdx.x] = v;
    __syncthreads();
    for (int off = 128; off > 0; off >>= 1) {
        if (threadIdx.x < off) s[threadIdx.x] += s[threadIdx.x + off];
        __syncthreads();
    }
    if (threadIdx.x == 0) bsums[blockIdx.x] = s[0];
}

__global__ void scan_bsums_kernel(int* __restrict__ bsums, int nb) {
    __shared__ int s[512];
    int v = (threadIdx.x < nb) ? bsums[threadIdx.x] : 0;
    s[threadIdx.x] = v;
    __syncthreads();
    for (int off = 1; off < 512; off <<= 1) {
        int t = (threadIdx.x >= off) ? s[threadIdx.x - off] : 0;
        __syncthreads();
        s[threadIdx.x] += t;
        __syncthreads();
    }
    if (threadIdx.x < nb) bsums[threadIdx.x] = s[threadIdx.x] - v;  // exclusive
}

__global__ void scan_final_kernel(const int* __restrict__ deg, const int* __restrict__ bsums,
                                  int* __restrict__ row_ptr, int* __restrict__ fill) {
    __shared__ int s[256];
    int i = blockIdx.x * 256 + threadIdx.x;
    int v = (i < N_NODES) ? deg[i] : 0;
    s[threadIdx.x] = v;
    __syncthreads();
    for (int off = 1; off < 256; off <<= 1) {
        int t = (threadIdx.x >= off) ? s[threadIdx.x - off] : 0;
        __syncthreads();
        s[threadIdx.x] += t;
        __syncthreads();
    }
    if (i < N_NODES) {
        int start = s[threadIdx.x] - v + bsums[blockIdx.x];
        row_ptr[i] = start;
        fill[i] = start;          // fill pre-initialized: atomicAdd gives pos directly
    }
    if (i == 0) row_ptr[N_NODES] = N_EDGES;
}

// ---------------- fused: gemm1 (x@w0, dis-scaled bf16 out) + fill_adj ----------------
// gemm blocks [0, GEMM_BLOCKS); fill blocks [GEMM_BLOCKS, GEMM_BLOCKS+FILL_BLOCKS).
// fill is 8 sequential c-range passes so the live adj window (~0.8 MB) stays L2-resident
// and partial-line writes merge.

__global__ __launch_bounds__(256) void gemm_fill_kernel(const float* __restrict__ A, int lda,
                                                        const float* __restrict__ W,
                                                        const float* __restrict__ dis,
                                                        unsigned short* __restrict__ Cb,
                                                        const int* __restrict__ ei,
                                                        int* __restrict__ fill,
                                                        int* __restrict__ adj) {
    __shared__ float As[32][128];
    __shared__ float Ws[128][128];
    int tx = threadIdx.x;

    if (blockIdx.x < GEMM_BLOCKS) {
        int rb = blockIdx.x * 32;
#pragma unroll
        for (int i = 0; i < 16; i++) {
            int f = tx + 256 * i;
            ((float4*)Ws)[f] = ((const float4*)W)[f];
        }
#pragma unroll
        for (int i = 0; i < 4; i++) {
            int idx = tx + 256 * i;
            int r = idx >> 5;
            int c4 = (idx & 31) << 2;
            *(float4*)&As[r][c4] = *(const float4*)&A[(size_t)(rb + r) * lda + c4];
        }
        __syncthreads();

        int col = (tx & 31) << 2;
        int rq = tx >> 5;
        float acc[4][4];
#pragma unroll
        for (int j = 0; j < 4; j++)
#pragma unroll
            for (int jj = 0; jj < 4; jj++) acc[j][jj] = 0.f;

        for (int k = 0; k < 128; k += 4) {
            float4 a[4];
#pragma unroll
            for (int j = 0; j < 4; j++) a[j] = *(const float4*)&As[rq + 8 * j][k];
#pragma unroll
            for (int kk = 0; kk < 4; kk++) {
                float4 w = *(const float4*)&Ws[k + kk][col];
#pragma unroll
                for (int j = 0; j < 4; j++) {
                    float av = ((const float*)&a[j])[kk];
                    acc[j][0] = fmaf(av, w.x, acc[j][0]);
                    acc[j][1] = fmaf(av, w.y, acc[j][1]);
                    acc[j][2] = fmaf(av, w.z, acc[j][2]);
                    acc[j][3] = fmaf(av, w.w, acc[j][3]);
                }
            }
        }
#pragma unroll
        for (int j = 0; j < 4; j++) {
            int r = rb + rq + 8 * j;
            float sc = dis[r];
            unsigned lo = f2bf(acc[j][0] * sc) | (f2bf(acc[j][1] * sc) << 16);
            unsigned hi = f2bf(acc[j][2] * sc) | (f2bf(acc[j][3] * sc) << 16);
            *(uint2*)&Cb[(size_t)r * 128 + col] = make_uint2(lo, hi);
        }
    } else {
        int fid = blockIdx.x - GEMM_BLOCKS;
        int pass = fid / FILL_CHUNKS;
        int chunk = fid - pass * FILL_CHUNKS;
        int lo = pass * FILL_RANGE, hi = lo + FILL_RANGE;
        int base = chunk * FILL_CHUNK + tx;
        int c[8], r[8];
#pragma unroll
        for (int j = 0; j < 8; j++) {
            int e = base + 256 * j;
            c[j] = (e < N_EDGES) ? ei[N_EDGES + e] : -1;
            r[j] = (e < N_EDGES) ? ei[e] : 0;
        }
#pragma unroll
        for (int j = 0; j < 8; j++) {
            if (c[j] >= lo && c[j] < hi) {
                int pos = atomicAdd(&fill[c[j]], 1);
                adj[pos] = r[j];
            }
        }
    }
}

// ---------------- standalone gemm (layer 2): Cb = (A@W)*dis, bf16 ----------------

__global__ __launch_bounds__(256) void gemm128_kernel(const float* __restrict__ A, int lda,
                                                      const float* __restrict__ W,
                                                      const float* __restrict__ dis,
                                                      unsigned short* __restrict__ Cb) {
    __shared__ float As[32][128];
    __shared__ float Ws[128][128];
    int tx = threadIdx.x;
    int rb = blockIdx.x * 32;
#pragma unroll
    for (int i = 0; i < 16; i++) {
        int f = tx + 256 * i;
        ((float4*)Ws)[f] = ((const float4*)W)[f];
    }
#pragma unroll
    for (int i = 0; i < 4; i++) {
        int idx = tx + 256 * i;
        int r = idx >> 5;
        int c4 = (idx & 31) << 2;
        *(float4*)&As[r][c4] = *(const float4*)&A[(size_t)(rb + r) * lda + c4];
    }
    __syncthreads();

    int col = (tx & 31) << 2;
    int rq = tx >> 5;
    float acc[4][4];
#pragma unroll
    for (int j = 0; j < 4; j++)
#pragma unroll
        for (int jj = 0; jj < 4; jj++) acc[j][jj] = 0.f;

    for (int k = 0; k < 128; k += 4) {
        float4 a[4];
#pragma unroll
        for (int j = 0; j < 4; j++) a[j] = *(const float4*)&As[rq + 8 * j][k];
#pragma unroll
        for (int kk = 0; kk < 4; kk++) {
            float4 w = *(const float4*)&Ws[k + kk][col];
#pragma unroll
            for (int j = 0; j < 4; j++) {
                float av = ((const float*)&a[j])[kk];
                acc[j][0] = fmaf(av, w.x, acc[j][0]);
                acc[j][1] = fmaf(av, w.y, acc[j][1]);
                acc[j][2] = fmaf(av, w.z, acc[j][2]);
                acc[j][3] = fmaf(av, w.w, acc[j][3]);
            }
        }
    }
#pragma unroll
    for (int j = 0; j < 4; j++) {
        int r = rb + rq + 8 * j;
        float sc = dis[r];
        unsigned lo = f2bf(acc[j][0] * sc) | (f2bf(acc[j][1] * sc) << 16);
        unsigned hi = f2bf(acc[j][2] * sc) | (f2bf(acc[j][3] * sc) << 16);
        *(uint2*)&Cb[(size_t)r * 128 + col] = make_uint2(lo, hi);
    }
}

// ---------------- aggregation ----------------
// hb rows are pre-scaled by dis[s]; per edge = pure add. out = relu(dc*(sum+self)+b).
// one wave per node, unroll 8.

__global__ __launch_bounds__(256) void agg_kernel(const unsigned* __restrict__ hb,
                                                  const float* __restrict__ dis,
                                                  const int* __restrict__ row_ptr,
                                                  const int* __restrict__ adj,
                                                  const float* __restrict__ bias,
                                                  float* __restrict__ out, int ldo) {
    int node = __builtin_amdgcn_readfirstlane(blockIdx.x * 4 + (threadIdx.x >> 6));
    int lane = threadIdx.x & 63;
    float dc = dis[node];
    int p0 = row_ptr[node], p1 = row_ptr[node + 1];

    unsigned sv = hb[(size_t)node * 64 + lane];
    float a0 = bflo(sv), a1 = bfhi(sv);   // self (already dis-scaled)
    float b0 = 0.f, b1 = 0.f, c0 = 0.f, c1 = 0.f, d0 = 0.f, d1 = 0.f;

    int p = p0;
    for (; p + 8 <= p1; p += 8) {
        int s0 = adj[p + 0], s1 = adj[p + 1], s2 = adj[p + 2], s3 = adj[p + 3];
        int s4 = adj[p + 4], s5 = adj[p + 5], s6 = adj[p + 6], s7 = adj[p + 7];
        unsigned v0 = hb[(size_t)s0 * 64 + lane];
        unsigned v1 = hb[(size_t)s1 * 64 + lane];
        unsigned v2 = hb[(size_t)s2 * 64 + lane];
        unsigned v3 = hb[(size_t)s3 * 64 + lane];
        unsigned v4 = hb[(size_t)s4 * 64 + lane];
        unsigned v5 = hb[(size_t)s5 * 64 + lane];
        unsigned v6 = hb[(size_t)s6 * 64 + lane];
        unsigned v7 = hb[(size_t)s7 * 64 + lane];
        a0 += bflo(v0); a1 += bfhi(v0);
        b0 += bflo(v1); b1 += bfhi(v1);
        c0 += bflo(v2); c1 += bfhi(v2);
        d0 += bflo(v3); d1 += bfhi(v3);
        a0 += bflo(v4); a1 += bfhi(v4);
        b0 += bflo(v5); b1 += bfhi(v5);
        c0 += bflo(v6); c1 += bfhi(v6);
        d0 += bflo(v7); d1 += bfhi(v7);
    }
    for (; p + 2 <= p1; p += 2) {
        int s0 = adj[p], s1 = adj[p + 1];
        unsigned v0 = hb[(size_t)s0 * 64 + lane];
        unsigned v1 = hb[(size_t)s1 * 64 + lane];
        a0 += bflo(v0); a1 += bfhi(v0);
        b0 += bflo(v1); b1 += bfhi(v1);
    }
    if (p < p1) {
        unsigned v = hb[(size_t)adj[p] * 64 + lane];
        c0 += bflo(v); c1 += bfhi(v);
    }

    float2 bi = *(const float2*)&bias[lane * 2];
    float r0 = fmaxf(fmaf(dc, (a0 + b0) + (c0 + d0), bi.x), 0.f);
    float r1 = fmaxf(fmaf(dc, (a1 + b1) + (c1 + d1), bi.y), 0.f);
    *(float2*)&out[(size_t)node * ldo + lane * 2] = make_float2(r0, r1);
}

// ---------------- classifier ----------------

__global__ __launch_bounds__(256) void classifier_kernel(const float* __restrict__ A, int lda,
                                                         const float* __restrict__ Wc,
                                                         const float* __restrict__ bc,
                                                         float* __restrict__ out1,
                                                         float* __restrict__ out2) {
    __shared__ float Hs[32][128];
    int tx = threadIdx.x;
    int rb = blockIdx.x * 32;
#pragma unroll
    for (int i = 0; i < 4; i++) {
        int idx = tx + 256 * i;
        int r = idx >> 5;
        int c4 = (idx & 31) << 2;
        *(float4*)&Hs[r][c4] = *(const float4*)&A[(size_t)(rb + r) * lda + c4];
    }
    __syncthreads();

    int j = tx & 63;
    int ry = tx >> 6;
    if (j < NC) {
        float acc[8];
#pragma unroll
        for (int i = 0; i < 8; i++) acc[i] = bc[j];
        for (int k = 0; k < 128; k++) {
            float w = Wc[(size_t)k * NC + j];
#pragma unroll
            for (int i = 0; i < 8; i++) acc[i] = fmaf(Hs[ry + 4 * i][k], w, acc[i]);
        }
#pragma unroll
        for (int i = 0; i < 8; i++) {
            int r = rb + ry + 4 * i;
            out1[(size_t)r * NC + j] = acc[i];
            out2[(size_t)r * 296 + j] = acc[i];
        }
    }
}

// ---------------- launch ----------------

extern "C" void kernel_launch(void* const* d_in, const int* in_sizes, int n_in,
                              void* d_out, int out_size, void* d_ws, size_t ws_size,
                              hipStream_t stream) {
    (void)in_sizes; (void)n_in; (void)out_size; (void)ws_size;

    const float* x     = (const float*)d_in[0];
    const int*   ei    = (const int*)d_in[1];
    const float* w0    = (const float*)d_in[2];
    const float* b0    = (const float*)d_in[3];
    const float* w1    = (const float*)d_in[4];
    const float* b1    = (const float*)d_in[5];
    const float* cls_w = (const float*)d_in[6];
    const float* cls_b = (const float*)d_in[7];

    float* logits = (float*)d_out;
    float* feat   = logits + (size_t)N_NODES * NC;   // [N,296]: h1 | h2 | logits

    char* ws = (char*)d_ws;
    int*            deg     = (int*)(ws + 0);
    float*          dis     = (float*)(ws + 400000);
    int*            row_ptr = (int*)(ws + 800000);
    int*            fill    = (int*)(ws + 1200016);
    int*            adj     = (int*)(ws + 1600016);
    unsigned short* hb      = (unsigned short*)(ws + 8000016);
    int*            bsums   = (int*)(ws + 59200016);

    const int NB = (N_NODES + 255) / 256;   // 391

    hipMemsetAsync(deg, 0, (size_t)N_NODES * 4, stream);

    count_deg_kernel<<<FILL_CHUNKS, 256, 0, stream>>>(ei, deg);
    scan_partial_kernel<<<NB, 256, 0, stream>>>(deg, bsums, dis);
    scan_bsums_kernel<<<1, 512, 0, stream>>>(bsums, NB);
    scan_final_kernel<<<NB, 256, 0, stream>>>(deg, bsums, row_ptr, fill);

    // fused: layer-1 GEMM + CSR fill (independent)
    gemm_fill_kernel<<<GEMM_BLOCKS + FILL_BLOCKS, 256, 0, stream>>>(
        x, 128, w0, dis, hb, ei, fill, adj);

    agg_kernel<<<N_NODES / 4, 256, 0, stream>>>((const unsigned*)hb, dis, row_ptr, adj, b0,
                                                feat + 0, 296);
    gemm128_kernel<<<GEMM_BLOCKS, 256, 0, stream>>>(feat, 296, w1, dis, hb);
    agg_kernel<<<N_NODES / 4, 256, 0, stream>>>((const unsigned*)hb, dis, row_ptr, adj, b1,
                                                feat + 128, 296);
    classifier_kernel<<<GEMM_BLOCKS, 256, 0, stream>>>(feat + 128, 296, cls_w, cls_b,
                                                       logits, feat + 256);
}